// Round 6
// baseline (205.439 us; speedup 1.0000x reference)
//
#include <hip/hip_runtime.h>
#include <hip/hip_bf16.h>

typedef __hip_bfloat16 bf16;
typedef short bf16x8 __attribute__((ext_vector_type(8)));
typedef float f32x4 __attribute__((ext_vector_type(4)));

#define NGRAPH 16
#define QSCALE 0.17677669529663687f
#define VT_LD 8192  // V^T leading dim: 16 graphs x 512 slots

struct __align__(16) bf8x { bf16 v[8]; };

// ---------------- K1: prep — x cast, weight transposes, graph offsets ----------------
__global__ __launch_bounds__(256) void k_prep(const float* __restrict__ x,
                                              const float* __restrict__ Wqkv,
                                              const float* __restrict__ Wout,
                                              const int* __restrict__ batch,
                                              bf16* __restrict__ xb,
                                              bf16* __restrict__ Wqkv_t,
                                              bf16* __restrict__ Wout_t,
                                              int* __restrict__ offs, int N) {
  int tid = blockIdx.x * 256 + threadIdx.x;
  int T = gridDim.x * 256;
  for (int i = tid; i < N * 256; i += T) xb[i] = __float2bfloat16(x[i]);
  for (int i = tid; i < 768 * 256; i += T) {
    int n = i >> 8, k = i & 255;
    Wqkv_t[i] = __float2bfloat16(Wqkv[k * 768 + n]);
  }
  for (int i = tid; i < 256 * 256; i += T) {
    int n = i >> 8, k = i & 255;
    Wout_t[i] = __float2bfloat16(Wout[k * 256 + n]);
  }
  for (int i = tid; i < N; i += T) {
    if (i == 0) { offs[0] = 0; offs[NGRAPH] = N; }
    else if (batch[i] != batch[i - 1]) offs[batch[i]] = i;
  }
}

// ---------------- K2: bias precompute — per-tile RoPE distance bias ----------------
// block = one (graph, 16q, 32j) tile; cos once per pair for ALL 8 heads; output
// bf16 tiles in exact MFMA C-fragment order: tile[h][lane][k], k=(jt<<2)|rr.
__global__ __launch_bounds__(256) void k_bias(const float* __restrict__ pos,
                                              const float* __restrict__ freqs,
                                              const float* __restrict__ Wrope,
                                              const int* __restrict__ offs,
                                              bf16* __restrict__ bias) {
  __shared__ float Sb[8][16][33];
  __shared__ float wf[16];
  __shared__ float Wr[16][8];
  int b = blockIdx.z;
  int off = offs[b], n = offs[b + 1] - off;
  int q0 = blockIdx.x * 16, j0 = blockIdx.y * 32;
  if (q0 >= n || j0 >= n) return;
  int t = threadIdx.x;
  if (t < 16) wf[t] = fabsf(freqs[t]);
  if (t < 128) Wr[t >> 3][t & 7] = Wrope[t];
  int tb = 0;
  for (int g = 0; g < b; ++g) {
    int ng = offs[g + 1] - offs[g];
    tb += ((ng + 15) >> 4) * ((ng + 31) >> 5);
  }
  int jtiles = (n + 31) >> 5;
  bf16* tile = bias + (size_t)(tb + (q0 >> 4) * jtiles + (j0 >> 5)) * 4096;
  int qs = t >> 5, j = t & 31;
  int jg = j0 + j; bool vj = jg < n;
  float jx, jy, jz;
  { int a = (vj ? off + jg : off) * 3; jx = pos[a]; jy = pos[a + 1]; jz = pos[a + 2]; }
  __syncthreads();
  #pragma unroll
  for (int e = 0; e < 2; ++e) {
    int q = qs + 8 * e; int qg = q0 + q; bool vq = qg < n;
    float bv[8];
    #pragma unroll
    for (int h = 0; h < 8; ++h) bv[h] = 0.f;
    if (vq && vj) {
      int a = (off + qg) * 3;
      float dx = pos[a] - jx, dy = pos[a + 1] - jy, dz = pos[a + 2] - jz;
      float dist = sqrtf(dx * dx + dy * dy + dz * dz);
      #pragma unroll
      for (int r = 0; r < 16; ++r) {
        float cv = __cosf(dist * wf[r]);
        #pragma unroll
        for (int h = 0; h < 8; ++h) bv[h] += cv * Wr[r][h];
      }
    }
    #pragma unroll
    for (int h = 0; h < 8; ++h) Sb[h][q][j] = (vq && vj) ? bv[h] : -1e30f;
  }
  __syncthreads();
  int w = t >> 6, l = t & 63, fq = l >> 4, fr = l & 15;
  #pragma unroll
  for (int hh = 0; hh < 2; ++hh) {
    int h = w * 2 + hh;
    __align__(16) bf16 pk[8];
    #pragma unroll
    for (int k = 0; k < 8; ++k)
      pk[k] = __float2bfloat16(Sb[h][fq * 4 + (k & 3)][(k >> 2) * 16 + fr]);
    *(bf16x8*)(tile + h * 512 + l * 8) = *(const bf16x8*)pk;
  }
}

// ---------------- K3: QKV GEMM, LDS-free MFMA. C bf16 (Q scaled) + V^T output ----------
__global__ __launch_bounds__(256) void k_gemm_qkv(const bf16* __restrict__ A,
                                                  const bf16* __restrict__ Bt,
                                                  const int* __restrict__ batch,
                                                  const int* __restrict__ offs,
                                                  bf16* __restrict__ C,
                                                  bf16* __restrict__ VT, int M) {
  __shared__ float tr[64][65];
  __shared__ int rowcol[64];
  int t = threadIdx.x, w = t >> 6, l = t & 63, fr = l & 15, fq = l >> 4;
  int m0 = blockIdx.x * 64, n0 = blockIdx.y * 64;
  bool isV = (n0 >= 512);
  if (isV && t < 64) {
    int m = m0 + t; if (m > M - 1) m = M - 1;
    int b = batch[m];
    rowcol[t] = b * 512 + (m - offs[b]);
  }
  int arow = m0 + w * 16 + fr; if (arow > M - 1) arow = M - 1;
  bf16x8 af[8];
  #pragma unroll
  for (int kt = 0; kt < 8; ++kt)
    af[kt] = *(const bf16x8*)(A + (size_t)arow * 256 + kt * 32 + fq * 8);
  f32x4 acc[4];
  #pragma unroll
  for (int nt = 0; nt < 4; ++nt) acc[nt] = (f32x4){0.f, 0.f, 0.f, 0.f};
  #pragma unroll
  for (int nt = 0; nt < 4; ++nt) {
    int brow = n0 + nt * 16 + fr;
    #pragma unroll
    for (int kt = 0; kt < 8; ++kt) {
      bf16x8 bf_ = *(const bf16x8*)(Bt + (size_t)brow * 256 + kt * 32 + fq * 8);
      acc[nt] = __builtin_amdgcn_mfma_f32_16x16x32_bf16(af[kt], bf_, acc[nt], 0, 0, 0);
    }
  }
  #pragma unroll
  for (int nt = 0; nt < 4; ++nt) {
    int col = n0 + nt * 16 + fr;
    float sc = (col < 256) ? QSCALE : 1.f;
    #pragma unroll
    for (int rr = 0; rr < 4; ++rr) {
      int m = m0 + w * 16 + fq * 4 + rr;
      if (m < M) C[(size_t)m * 768 + col] = __float2bfloat16(acc[nt][rr] * sc);
    }
  }
  if (isV) {
    #pragma unroll
    for (int nt = 0; nt < 4; ++nt)
      #pragma unroll
      for (int rr = 0; rr < 4; ++rr)
        tr[nt * 16 + fr][w * 16 + fq * 4 + rr] = acc[nt][rr];
    __syncthreads();
    int c = t >> 2, r0 = (t & 3) * 16;
    int dg = (n0 - 512) + c;
    #pragma unroll
    for (int i = 0; i < 16; ++i) {
      int r = r0 + i;
      VT[(size_t)dg * VT_LD + rowcol[r]] = __float2bfloat16(tr[c][r]);
    }
  }
}

// ---------------- K4: MFMA flash attention — barrier-free, no-max softmax ----------------
// block = (q-tile 16, graph, head-half of 4). 4 waves, wave = one head.
__global__ __launch_bounds__(256) void k_attn(const bf16* __restrict__ QKVb,
                                              const bf16* __restrict__ VT,
                                              const bf16* __restrict__ bias,
                                              const int* __restrict__ offs,
                                              bf16* __restrict__ Ob) {
  __shared__ __align__(16) bf16 Pt[4][16][40];
  int b = blockIdx.y, hbase = blockIdx.z * 4;
  int off = offs[b], n = offs[b + 1] - off;
  int q0 = blockIdx.x * 16;
  if (q0 >= n) return;
  int t = threadIdx.x, w = t >> 6, l = t & 63, fr = l & 15, fq = l >> 4;
  int h = hbase + w;
  int tb = 0;
  for (int g = 0; g < b; ++g) {
    int ng = offs[g + 1] - offs[g];
    tb += ((ng + 15) >> 4) * ((ng + 31) >> 5);
  }
  int jtiles = (n + 31) >> 5;
  const bf16* btile = bias + (size_t)(tb + (q0 >> 4) * jtiles) * 4096 + h * 512 + l * 8;
  const bf16* Kb = QKVb + (size_t)off * 768 + 256 + h * 32 + fq * 8;
  const bf16* Vb = VT + (size_t)(h * 32 + fr) * VT_LD + b * 512 + fq * 8;
  int qrow = q0 + fr; bool qv = qrow < n;
  bf16x8 aq = *(const bf16x8*)(QKVb + (size_t)(qv ? off + qrow : off) * 768 + h * 32 + fq * 8);
  if (!qv) aq = (bf16x8){0, 0, 0, 0, 0, 0, 0, 0};
  f32x4 Oa[2];
  Oa[0] = (f32x4){0.f, 0.f, 0.f, 0.f}; Oa[1] = (f32x4){0.f, 0.f, 0.f, 0.f};
  float lacc[4] = {0.f, 0.f, 0.f, 0.f};

#define LOADT(JT, B_, K0_, K1_, V0_, V1_) do {                                   \
    int _jt = (JT); int _k0 = _jt * 32 + fr, _k1 = _k0 + 16;                     \
    B_ = *(const bf8x*)(btile + (size_t)_jt * 4096);                             \
    K0_ = *(const bf16x8*)(Kb + (size_t)((_k0 < n) ? _k0 : 0) * 768);            \
    K1_ = *(const bf16x8*)(Kb + (size_t)((_k1 < n) ? _k1 : 0) * 768);            \
    V0_ = *(const bf16x8*)(Vb + _jt * 32);                                       \
    V1_ = *(const bf16x8*)(Vb + (size_t)16 * VT_LD + _jt * 32);                  \
  } while (0)

  bf8x cb; bf16x8 ck0, ck1, cv0, cv1;
  LOADT(0, cb, ck0, ck1, cv0, cv1);
  for (int jt = 0; jt < jtiles; ++jt) {
    bf8x nb; bf16x8 nk0, nk1, nv0, nv1;
    if (jt + 1 < jtiles) LOADT(jt + 1, nb, nk0, nk1, nv0, nv1);
    f32x4 z = {0.f, 0.f, 0.f, 0.f};
    f32x4 S0 = __builtin_amdgcn_mfma_f32_16x16x32_bf16(aq, ck0, z, 0, 0, 0);
    f32x4 S1 = __builtin_amdgcn_mfma_f32_16x16x32_bf16(aq, ck1, z, 0, 0, 0);
    #pragma unroll
    for (int k = 0; k < 8; ++k) {
      int jti = k >> 2, rr = k & 3;
      float s = (jti ? S1[rr] : S0[rr]) + __bfloat162float(cb.v[k]);
      float p = __expf(s);
      lacc[rr] += p;
      Pt[w][fq * 4 + rr][jti * 16 + fr] = __float2bfloat16(p);
    }
    bf16x8 ap = *(const bf16x8*)&Pt[w][fr][fq * 8];
    Oa[0] = __builtin_amdgcn_mfma_f32_16x16x32_bf16(ap, cv0, Oa[0], 0, 0, 0);
    Oa[1] = __builtin_amdgcn_mfma_f32_16x16x32_bf16(ap, cv1, Oa[1], 0, 0, 0);
    cb = nb; ck0 = nk0; ck1 = nk1; cv0 = nv0; cv1 = nv1;
  }
#undef LOADT
  #pragma unroll
  for (int rr = 0; rr < 4; ++rr) {
    #pragma unroll
    for (int m2 = 1; m2 <= 8; m2 <<= 1) lacc[rr] += __shfl_xor(lacc[rr], m2);
  }
  #pragma unroll
  for (int dh = 0; dh < 2; ++dh)
    #pragma unroll
    for (int rr = 0; rr < 4; ++rr) {
      int row = q0 + fq * 4 + rr;
      if (row < n)
        Ob[(size_t)(off + row) * 256 + h * 32 + dh * 16 + fr] =
            __float2bfloat16(Oa[dh][rr] / lacc[rr]);
    }
}

// ---------------- K4-fallback: R5 in-kernel-bias attention (small ws) ----------------
__global__ __launch_bounds__(256) void k_attn_fb(const float* __restrict__ pos,
                                                 const float* __restrict__ freqs,
                                                 const float* __restrict__ Wrope,
                                                 const bf16* __restrict__ QKVb,
                                                 const bf16* __restrict__ VT,
                                                 const int* __restrict__ offs,
                                                 bf16* __restrict__ Ob) {
  __shared__ float Sb[2][4][16][34];
  __shared__ __align__(16) bf16 Pt[4][16][40];
  __shared__ float wf[16];
  __shared__ float Wr[16][4];
  int b = blockIdx.y, hbase = blockIdx.z * 4;
  int off = offs[b], n = offs[b + 1] - off;
  int q0 = blockIdx.x * 16;
  if (q0 >= n) return;
  int t = threadIdx.x, w = t >> 6, l = t & 63, fr = l & 15, fq = l >> 4;
  int h = hbase + w;
  if (t < 16) wf[t] = fabsf(freqs[t]);
  if (t < 64) Wr[t >> 2][t & 3] = Wrope[(t >> 2) * 8 + hbase + (t & 3)];
  int qrow = q0 + fr; bool qv = qrow < n;
  bf16x8 aq = *(const bf16x8*)(QKVb + (size_t)((qv ? off + qrow : off)) * 768 + h * 32 + fq * 8);
  if (!qv) aq = (bf16x8){0, 0, 0, 0, 0, 0, 0, 0};
  int bq = t >> 5, bj = t & 31;
  float qpx[2], qpy[2], qpz[2]; bool bqv[2];
  #pragma unroll
  for (int e = 0; e < 2; ++e) {
    int qq = q0 + bq + 8 * e; bqv[e] = qq < n;
    int a = (bqv[e] ? off + qq : off) * 3;
    qpx[e] = pos[a]; qpy[e] = pos[a + 1]; qpz[e] = pos[a + 2];
  }
  float m_st[4], l_st[4]; f32x4 Oa[2];
  #pragma unroll
  for (int rr = 0; rr < 4; ++rr) { m_st[rr] = -1e30f; l_st[rr] = 0.f; }
  Oa[0] = (f32x4){0.f, 0.f, 0.f, 0.f}; Oa[1] = (f32x4){0.f, 0.f, 0.f, 0.f};
  __syncthreads();
  int par = 0;
  for (int j0 = 0; j0 < n; j0 += 32, par ^= 1) {
    {
      int jg = j0 + bj; bool vj = jg < n;
      int a = (vj ? off + jg : off) * 3;
      float jx = pos[a], jy = pos[a + 1], jz = pos[a + 2];
      #pragma unroll
      for (int e = 0; e < 2; ++e) {
        float bv0 = 0.f, bv1 = 0.f, bv2 = 0.f, bv3 = 0.f;
        if (vj && bqv[e]) {
          float dx = qpx[e] - jx, dy = qpy[e] - jy, dz = qpz[e] - jz;
          float dist = sqrtf(dx * dx + dy * dy + dz * dz);
          #pragma unroll
          for (int r = 0; r < 16; ++r) {
            float cv = __cosf(dist * wf[r]);
            bv0 += cv * Wr[r][0]; bv1 += cv * Wr[r][1];
            bv2 += cv * Wr[r][2]; bv3 += cv * Wr[r][3];
          }
        }
        int qi = bq + 8 * e;
        Sb[par][0][qi][bj] = vj ? bv0 : -1e30f;
        Sb[par][1][qi][bj] = vj ? bv1 : -1e30f;
        Sb[par][2][qi][bj] = vj ? bv2 : -1e30f;
        Sb[par][3][qi][bj] = vj ? bv3 : -1e30f;
      }
    }
    __syncthreads();
    f32x4 Sv[2];
    #pragma unroll
    for (int jt = 0; jt < 2; ++jt) {
      int krow = j0 + jt * 16 + fr;
      bf16x8 bk = *(const bf16x8*)(QKVb + (size_t)((krow < n) ? off + krow : off) * 768 + 256 + h * 32 + fq * 8);
      f32x4 z = {0.f, 0.f, 0.f, 0.f};
      Sv[jt] = __builtin_amdgcn_mfma_f32_16x16x32_bf16(aq, bk, z, 0, 0, 0);
      #pragma unroll
      for (int rr = 0; rr < 4; ++rr) Sv[jt][rr] += Sb[par][w][fq * 4 + rr][jt * 16 + fr];
    }
    #pragma unroll
    for (int rr = 0; rr < 4; ++rr) {
      float mrow = fmaxf(Sv[0][rr], Sv[1][rr]);
      #pragma unroll
      for (int m2 = 1; m2 <= 8; m2 <<= 1) mrow = fmaxf(mrow, __shfl_xor(mrow, m2));
      float mnew = fmaxf(m_st[rr], mrow);
      float al = __expf(m_st[rr] - mnew);
      m_st[rr] = mnew;
      float p0 = __expf(Sv[0][rr] - mnew), p1 = __expf(Sv[1][rr] - mnew);
      Sv[0][rr] = p0; Sv[1][rr] = p1;
      float rs = p0 + p1;
      #pragma unroll
      for (int m2 = 1; m2 <= 8; m2 <<= 1) rs += __shfl_xor(rs, m2);
      l_st[rr] = l_st[rr] * al + rs;
      Oa[0][rr] *= al; Oa[1][rr] *= al;
    }
    #pragma unroll
    for (int jt = 0; jt < 2; ++jt)
      #pragma unroll
      for (int rr = 0; rr < 4; ++rr)
        Pt[w][fq * 4 + rr][jt * 16 + fr] = __float2bfloat16(Sv[jt][rr]);
    bf16x8 ap = *(const bf16x8*)&Pt[w][fr][fq * 8];
    #pragma unroll
    for (int dh = 0; dh < 2; ++dh) {
      bf16x8 bv = *(const bf16x8*)(VT + (size_t)(h * 32 + dh * 16 + fr) * VT_LD + b * 512 + j0 + fq * 8);
      Oa[dh] = __builtin_amdgcn_mfma_f32_16x16x32_bf16(ap, bv, Oa[dh], 0, 0, 0);
    }
  }
  #pragma unroll
  for (int dh = 0; dh < 2; ++dh)
    #pragma unroll
    for (int rr = 0; rr < 4; ++rr) {
      int row = q0 + fq * 4 + rr;
      if (row < n)
        Ob[(size_t)(off + row) * 256 + h * 32 + dh * 16 + fr] =
            __float2bfloat16(Oa[dh][rr] / l_st[rr]);
    }
}

// ---------------- K5: out-proj GEMM + residual + LayerNorm fused ----------------
__global__ __launch_bounds__(256) void k_gemm_out_ln(const bf16* __restrict__ A,
                                                     const bf16* __restrict__ Bt,
                                                     const float* __restrict__ x,
                                                     const float* __restrict__ gamma,
                                                     const float* __restrict__ beta,
                                                     float* __restrict__ out, int M) {
  int t = threadIdx.x, w = t >> 6, l = t & 63, fr = l & 15, fq = l >> 4;
  int m0 = blockIdx.x * 64;
  int arow = m0 + w * 16 + fr; if (arow > M - 1) arow = M - 1;
  bf16x8 af[8];
  #pragma unroll
  for (int kt = 0; kt < 8; ++kt)
    af[kt] = *(const bf16x8*)(A + (size_t)arow * 256 + kt * 32 + fq * 8);
  f32x4 acc[16];
  #pragma unroll
  for (int nt = 0; nt < 16; ++nt) {
    acc[nt] = (f32x4){0.f, 0.f, 0.f, 0.f};
    int brow = nt * 16 + fr;
    #pragma unroll
    for (int kt = 0; kt < 8; ++kt) {
      bf16x8 bf_ = *(const bf16x8*)(Bt + (size_t)brow * 256 + kt * 32 + fq * 8);
      acc[nt] = __builtin_amdgcn_mfma_f32_16x16x32_bf16(af[kt], bf_, acc[nt], 0, 0, 0);
    }
  }
  float g[16], bb[16];
  #pragma unroll
  for (int nt = 0; nt < 16; ++nt) { g[nt] = gamma[nt * 16 + fr]; bb[nt] = beta[nt * 16 + fr]; }
  #pragma unroll
  for (int rr = 0; rr < 4; ++rr) {
    int row = m0 + w * 16 + fq * 4 + rr;
    int rc = (row < M) ? row : (M - 1);
    float vv[16];
    float s = 0.f, ss = 0.f;
    #pragma unroll
    for (int nt = 0; nt < 16; ++nt) {
      float y = acc[nt][rr] + x[(size_t)rc * 256 + nt * 16 + fr];
      vv[nt] = y; s += y; ss += y * y;
    }
    #pragma unroll
    for (int m2 = 1; m2 <= 8; m2 <<= 1) { s += __shfl_xor(s, m2); ss += __shfl_xor(ss, m2); }
    float mean = s * (1.f / 256.f);
    float var = ss * (1.f / 256.f) - mean * mean;
    float rstd = rsqrtf(var + 1e-5f);
    if (row < M) {
      #pragma unroll
      for (int nt = 0; nt < 16; ++nt)
        out[(size_t)row * 256 + nt * 16 + fr] = g[nt] * (vv[nt] - mean) * rstd + bb[nt];
    }
  }
}

extern "C" void kernel_launch(void* const* d_in, const int* in_sizes, int n_in,
                              void* d_out, int out_size, void* d_ws, size_t ws_size,
                              hipStream_t stream) {
  (void)n_in; (void)out_size;
  const float* x     = (const float*)d_in[0];
  const float* pos   = (const float*)d_in[1];
  const int*   batch = (const int*)d_in[2];
  const float* Wqkv  = (const float*)d_in[3];
  const float* Wout  = (const float*)d_in[4];
  const float* freqs = (const float*)d_in[5];
  const float* Wrope = (const float*)d_in[6];
  const float* gamma = (const float*)d_in[7];
  const float* beta  = (const float*)d_in[8];
  float* out = (float*)d_out;

  int N = in_sizes[0] / 256;  // 6137

  char* base = (char*)d_ws;
  int*   offs   = (int*)base;
  bf16*  QKVb   = (bf16*)(base + 1024);         // N*768*2  = 9,426,432
  bf16*  VT     = (bf16*)(base + 9427456);      // 4,194,304
  bf16*  xb     = (bf16*)(base + 13621760);     // N*256*2  = 3,142,144
  bf16*  Wqkv_t = (bf16*)(base + 16763904);     // 393,216
  bf16*  Wout_t = (bf16*)(base + 17157120);     // 131,072
  bf16*  biasb  = (bf16*)(base + 17288192);     // ~41.3 MB (tiled bias)
  bf16*  Ob     = xb;                           // xb dead after gemm_qkv

  bool fast = ws_size >= (size_t)58700000;      // 17,288,192 + 41,312,256 needed

  int MB = (N + 63) / 64;  // 96
  k_prep<<<1024, 256, 0, stream>>>(x, Wqkv, Wout, batch, xb, Wqkv_t, Wout_t, offs, N);
  if (fast)
    k_bias<<<dim3(32, 16, NGRAPH), 256, 0, stream>>>(pos, freqs, Wrope, offs, biasb);
  k_gemm_qkv<<<dim3(MB, 12), 256, 0, stream>>>(xb, Wqkv_t, batch, offs, QKVb, VT, N);
  if (fast)
    k_attn<<<dim3(32, NGRAPH, 2), 256, 0, stream>>>(QKVb, VT, biasb, offs, Ob);
  else
    k_attn_fb<<<dim3(32, NGRAPH, 2), 256, 0, stream>>>(pos, freqs, Wrope, QKVb, VT, offs, Ob);
  k_gemm_out_ln<<<MB, 256, 0, stream>>>(Ob, Wout_t, x, gamma, beta, out, N);
}

// Round 7
// 189.295 us; speedup vs baseline: 1.0853x; 1.0853x over previous
//
#include <hip/hip_runtime.h>
#include <hip/hip_bf16.h>

typedef __hip_bfloat16 bf16;
typedef short bf16x8 __attribute__((ext_vector_type(8)));
typedef float f32x4 __attribute__((ext_vector_type(4)));

#define NGRAPH 16
#define QSCALE 0.17677669529663687f
#define VT_LD 8192  // V^T leading dim: 16 graphs x 512 slots

struct __align__(16) bf8x { bf16 v[8]; };

// load 8 consecutive f32 and convert to a bf16x8 A/B fragment
__device__ __forceinline__ bf16x8 ldcvt8(const float* p) {
  float4 u = *(const float4*)p, v = *(const float4*)(p + 4);
  __align__(16) bf16 tmp[8];
  tmp[0] = __float2bfloat16(u.x); tmp[1] = __float2bfloat16(u.y);
  tmp[2] = __float2bfloat16(u.z); tmp[3] = __float2bfloat16(u.w);
  tmp[4] = __float2bfloat16(v.x); tmp[5] = __float2bfloat16(v.y);
  tmp[6] = __float2bfloat16(v.z); tmp[7] = __float2bfloat16(v.w);
  return *(const bf16x8*)tmp;
}

// ---------------- K1: W transposes (LDS-tiled, coalesced) + graph offsets ----------------
// grid: 48 Wqkv tiles + 16 Wout tiles + 1 offs block = 65 blocks
__global__ __launch_bounds__(256) void k_pre(const float* __restrict__ Wqkv,
                                             const float* __restrict__ Wout,
                                             const int* __restrict__ batch,
                                             bf16* __restrict__ Wqkv_t,
                                             bf16* __restrict__ Wout_t,
                                             int* __restrict__ offs, int N) {
  __shared__ float ld[64][65];
  int bid = blockIdx.x, t = threadIdx.x;
  int c = t & 63, r0 = t >> 6;
  if (bid < 48) {  // Wqkv [256][768] -> Wqkv_t [768][256]
    int k0 = (bid & 3) * 64, n0 = (bid >> 2) * 64;
    #pragma unroll
    for (int r = r0; r < 64; r += 4) ld[r][c] = Wqkv[(size_t)(k0 + r) * 768 + n0 + c];
    __syncthreads();
    #pragma unroll
    for (int r = r0; r < 64; r += 4)
      Wqkv_t[(size_t)(n0 + r) * 256 + k0 + c] = __float2bfloat16(ld[c][r]);
  } else if (bid < 64) {  // Wout [256][256] -> Wout_t [256][256]
    int b2 = bid - 48;
    int k0 = (b2 & 3) * 64, n0 = (b2 >> 2) * 64;
    #pragma unroll
    for (int r = r0; r < 64; r += 4) ld[r][c] = Wout[(size_t)(k0 + r) * 256 + n0 + c];
    __syncthreads();
    #pragma unroll
    for (int r = r0; r < 64; r += 4)
      Wout_t[(size_t)(n0 + r) * 256 + k0 + c] = __float2bfloat16(ld[c][r]);
  } else {  // offsets from sorted batch ids
    for (int i = t; i < N; i += 256) {
      if (i == 0) { offs[0] = 0; offs[NGRAPH] = N; }
      else if (batch[i] != batch[i - 1]) offs[batch[i]] = i;
    }
  }
}

// ---------------- K2: merged [QKV GEMM (x f32 direct) | bias precompute] ----------------
// blocks [0, MBm*12): 64x64 GEMM tiles; blocks [MBm*12, +8192): bias tiles.
__global__ __launch_bounds__(256) void k_mid(const float* __restrict__ x,
                                             const bf16* __restrict__ Wqkv_t,
                                             const float* __restrict__ pos,
                                             const float* __restrict__ freqs,
                                             const float* __restrict__ Wrope,
                                             const int* __restrict__ batch,
                                             const int* __restrict__ offs,
                                             bf16* __restrict__ QKVb,
                                             bf16* __restrict__ VT,
                                             bf16* __restrict__ bias,
                                             int N, int MBm) {
  __shared__ __align__(16) char smem[16896];
  __shared__ float wf[16];
  __shared__ float Wr[16][8];
  int t = threadIdx.x, bid = blockIdx.x;
  int nbg = MBm * 12;
  if (bid < nbg) {
    // ---------------- GEMM role ----------------
    float (*tr)[65] = (float(*)[65])smem;            // 64x65x4 = 16640
    int* rowcol = (int*)(smem + 16640);              // 64x4    = 256
    int w = t >> 6, l = t & 63, fr = l & 15, fq = l >> 4;
    int m0 = (bid % MBm) * 64, n0 = (bid / MBm) * 64;
    bool isV = (n0 >= 512);
    if (isV && t < 64) {
      int m = m0 + t; if (m > N - 1) m = N - 1;
      int b = batch[m];
      rowcol[t] = b * 512 + (m - offs[b]);
    }
    int arow = m0 + w * 16 + fr; if (arow > N - 1) arow = N - 1;
    bf16x8 af[8];
    #pragma unroll
    for (int kt = 0; kt < 8; ++kt)
      af[kt] = ldcvt8(x + (size_t)arow * 256 + kt * 32 + fq * 8);
    f32x4 acc[4];
    #pragma unroll
    for (int nt = 0; nt < 4; ++nt) acc[nt] = (f32x4){0.f, 0.f, 0.f, 0.f};
    #pragma unroll
    for (int nt = 0; nt < 4; ++nt) {
      int brow = n0 + nt * 16 + fr;
      #pragma unroll
      for (int kt = 0; kt < 8; ++kt) {
        bf16x8 bf_ = *(const bf16x8*)(Wqkv_t + (size_t)brow * 256 + kt * 32 + fq * 8);
        acc[nt] = __builtin_amdgcn_mfma_f32_16x16x32_bf16(af[kt], bf_, acc[nt], 0, 0, 0);
      }
    }
    #pragma unroll
    for (int nt = 0; nt < 4; ++nt) {
      int col = n0 + nt * 16 + fr;
      float sc = (col < 256) ? QSCALE : 1.f;
      #pragma unroll
      for (int rr = 0; rr < 4; ++rr) {
        int m = m0 + w * 16 + fq * 4 + rr;
        if (m < N) QKVb[(size_t)m * 768 + col] = __float2bfloat16(acc[nt][rr] * sc);
      }
    }
    if (isV) {
      #pragma unroll
      for (int nt = 0; nt < 4; ++nt)
        #pragma unroll
        for (int rr = 0; rr < 4; ++rr)
          tr[nt * 16 + fr][w * 16 + fq * 4 + rr] = acc[nt][rr];
      __syncthreads();
      int c = t >> 2, r0 = (t & 3) * 16;
      int dg = (n0 - 512) + c;
      #pragma unroll
      for (int i = 0; i < 16; ++i) {
        int r = r0 + i;
        VT[(size_t)dg * VT_LD + rowcol[r]] = __float2bfloat16(tr[c][r]);
      }
    }
  } else {
    // ---------------- bias role: one (graph, 16q, 32j) tile ----------------
    float (*Sb)[16][33] = (float(*)[16][33])smem;    // 8x16x33x4 = 16896
    int b2 = bid - nbg;
    int b = b2 >> 9;
    int q0 = (b2 & 31) * 16, j0 = ((b2 >> 5) & 15) * 32;
    int off = offs[b], n = offs[b + 1] - off;
    if (q0 >= n || j0 >= n) return;
    if (t < 16) wf[t] = fabsf(freqs[t]);
    if (t < 128) Wr[t >> 3][t & 7] = Wrope[t];
    int tb = 0;
    for (int g = 0; g < b; ++g) {
      int ng = offs[g + 1] - offs[g];
      tb += ((ng + 15) >> 4) * ((ng + 31) >> 5);
    }
    int jtiles = (n + 31) >> 5;
    bf16* tile = bias + (size_t)(tb + (q0 >> 4) * jtiles + (j0 >> 5)) * 4096;
    int qs = t >> 5, j = t & 31;
    int jg = j0 + j; bool vj = jg < n;
    float jx, jy, jz;
    { int a = (vj ? off + jg : off) * 3; jx = pos[a]; jy = pos[a + 1]; jz = pos[a + 2]; }
    __syncthreads();
    #pragma unroll
    for (int e = 0; e < 2; ++e) {
      int q = qs + 8 * e; int qg = q0 + q; bool vq = qg < n;
      float bv[8];
      #pragma unroll
      for (int h = 0; h < 8; ++h) bv[h] = 0.f;
      if (vq && vj) {
        int a = (off + qg) * 3;
        float dx = pos[a] - jx, dy = pos[a + 1] - jy, dz = pos[a + 2] - jz;
        float dist = sqrtf(dx * dx + dy * dy + dz * dz);
        #pragma unroll
        for (int r = 0; r < 16; ++r) {
          float cv = __cosf(dist * wf[r]);
          #pragma unroll
          for (int h = 0; h < 8; ++h) bv[h] += cv * Wr[r][h];
        }
      }
      #pragma unroll
      for (int h = 0; h < 8; ++h) Sb[h][q][j] = (vq && vj) ? bv[h] : -1e30f;
    }
    __syncthreads();
    int w = t >> 6, l = t & 63, fq = l >> 4, fr = l & 15;
    #pragma unroll
    for (int hh = 0; hh < 2; ++hh) {
      int h = w * 2 + hh;
      __align__(16) bf16 pk[8];
      #pragma unroll
      for (int k = 0; k < 8; ++k)
        pk[k] = __float2bfloat16(Sb[h][fq * 4 + (k & 3)][(k >> 2) * 16 + fr]);
      *(bf16x8*)(tile + h * 512 + l * 8) = *(const bf16x8*)pk;
    }
  }
}

// ---------------- K3: MFMA flash attention — barrier-free, no-max softmax ----------------
__global__ __launch_bounds__(256) void k_attn(const bf16* __restrict__ QKVb,
                                              const bf16* __restrict__ VT,
                                              const bf16* __restrict__ bias,
                                              const int* __restrict__ offs,
                                              bf16* __restrict__ Ob) {
  __shared__ __align__(16) bf16 Pt[4][16][40];
  int b = blockIdx.y, hbase = blockIdx.z * 4;
  int off = offs[b], n = offs[b + 1] - off;
  int q0 = blockIdx.x * 16;
  if (q0 >= n) return;
  int t = threadIdx.x, w = t >> 6, l = t & 63, fr = l & 15, fq = l >> 4;
  int h = hbase + w;
  int tb = 0;
  for (int g = 0; g < b; ++g) {
    int ng = offs[g + 1] - offs[g];
    tb += ((ng + 15) >> 4) * ((ng + 31) >> 5);
  }
  int jtiles = (n + 31) >> 5;
  const bf16* btile = bias + (size_t)(tb + (q0 >> 4) * jtiles) * 4096 + h * 512 + l * 8;
  const bf16* Kb = QKVb + (size_t)off * 768 + 256 + h * 32 + fq * 8;
  const bf16* Vb = VT + (size_t)(h * 32 + fr) * VT_LD + b * 512 + fq * 8;
  int qrow = q0 + fr; bool qv = qrow < n;
  bf16x8 aq = *(const bf16x8*)(QKVb + (size_t)(qv ? off + qrow : off) * 768 + h * 32 + fq * 8);
  if (!qv) aq = (bf16x8){0, 0, 0, 0, 0, 0, 0, 0};
  f32x4 Oa[2];
  Oa[0] = (f32x4){0.f, 0.f, 0.f, 0.f}; Oa[1] = (f32x4){0.f, 0.f, 0.f, 0.f};
  float lacc[4] = {0.f, 0.f, 0.f, 0.f};

#define LOADT(JT, B_, K0_, K1_, V0_, V1_) do {                                   \
    int _jt = (JT); int _k0 = _jt * 32 + fr, _k1 = _k0 + 16;                     \
    B_ = *(const bf8x*)(btile + (size_t)_jt * 4096);                             \
    K0_ = *(const bf16x8*)(Kb + (size_t)((_k0 < n) ? _k0 : 0) * 768);            \
    K1_ = *(const bf16x8*)(Kb + (size_t)((_k1 < n) ? _k1 : 0) * 768);            \
    V0_ = *(const bf16x8*)(Vb + _jt * 32);                                       \
    V1_ = *(const bf16x8*)(Vb + (size_t)16 * VT_LD + _jt * 32);                  \
  } while (0)

  bf8x cb; bf16x8 ck0, ck1, cv0, cv1;
  LOADT(0, cb, ck0, ck1, cv0, cv1);
  for (int jt = 0; jt < jtiles; ++jt) {
    bf8x nb; bf16x8 nk0, nk1, nv0, nv1;
    if (jt + 1 < jtiles) LOADT(jt + 1, nb, nk0, nk1, nv0, nv1);
    f32x4 z = {0.f, 0.f, 0.f, 0.f};
    f32x4 S0 = __builtin_amdgcn_mfma_f32_16x16x32_bf16(aq, ck0, z, 0, 0, 0);
    f32x4 S1 = __builtin_amdgcn_mfma_f32_16x16x32_bf16(aq, ck1, z, 0, 0, 0);
    #pragma unroll
    for (int k = 0; k < 8; ++k) {
      int jti = k >> 2, rr = k & 3;
      float s = (jti ? S1[rr] : S0[rr]) + __bfloat162float(cb.v[k]);
      float p = __expf(s);
      lacc[rr] += p;
      Pt[w][fq * 4 + rr][jti * 16 + fr] = __float2bfloat16(p);
    }
    bf16x8 ap = *(const bf16x8*)&Pt[w][fr][fq * 8];
    Oa[0] = __builtin_amdgcn_mfma_f32_16x16x32_bf16(ap, cv0, Oa[0], 0, 0, 0);
    Oa[1] = __builtin_amdgcn_mfma_f32_16x16x32_bf16(ap, cv1, Oa[1], 0, 0, 0);
    cb = nb; ck0 = nk0; ck1 = nk1; cv0 = nv0; cv1 = nv1;
  }
#undef LOADT
  #pragma unroll
  for (int rr = 0; rr < 4; ++rr) {
    #pragma unroll
    for (int m2 = 1; m2 <= 8; m2 <<= 1) lacc[rr] += __shfl_xor(lacc[rr], m2);
  }
  #pragma unroll
  for (int dh = 0; dh < 2; ++dh)
    #pragma unroll
    for (int rr = 0; rr < 4; ++rr) {
      int row = q0 + fq * 4 + rr;
      if (row < n)
        Ob[(size_t)(off + row) * 256 + h * 32 + dh * 16 + fr] =
            __float2bfloat16(Oa[dh][rr] / lacc[rr]);
    }
}

// ---------------- K4: out-proj GEMM + residual + LN, 16 rows/block (384 blocks) ----------
__global__ __launch_bounds__(256) void k_out_ln(const bf16* __restrict__ A,
                                                const bf16* __restrict__ Bt,
                                                const float* __restrict__ x,
                                                const float* __restrict__ gamma,
                                                const float* __restrict__ beta,
                                                float* __restrict__ out, int M) {
  __shared__ float ps[4][16], pss[4][16];
  int t = threadIdx.x, w = t >> 6, l = t & 63, fr = l & 15, fq = l >> 4;
  int m0 = blockIdx.x * 16;
  int arow = m0 + fr; if (arow > M - 1) arow = M - 1;
  bf16x8 af[8];
  #pragma unroll
  for (int kt = 0; kt < 8; ++kt)
    af[kt] = *(const bf16x8*)(A + (size_t)arow * 256 + kt * 32 + fq * 8);
  f32x4 acc[4];
  #pragma unroll
  for (int nt = 0; nt < 4; ++nt) {
    acc[nt] = (f32x4){0.f, 0.f, 0.f, 0.f};
    int brow = w * 64 + nt * 16 + fr;
    #pragma unroll
    for (int kt = 0; kt < 8; ++kt) {
      bf16x8 bf_ = *(const bf16x8*)(Bt + (size_t)brow * 256 + kt * 32 + fq * 8);
      acc[nt] = __builtin_amdgcn_mfma_f32_16x16x32_bf16(af[kt], bf_, acc[nt], 0, 0, 0);
    }
  }
  // residual + per-wave LN partials (rows = fq*4+rr, cols = w*64+nt*16+fr)
  float y[4][4];
  #pragma unroll
  for (int rr = 0; rr < 4; ++rr) {
    int row = m0 + fq * 4 + rr;
    int rc = (row < M) ? row : (M - 1);
    float s = 0.f, ss = 0.f;
    #pragma unroll
    for (int nt = 0; nt < 4; ++nt) {
      float v = acc[nt][rr] + x[(size_t)rc * 256 + w * 64 + nt * 16 + fr];
      y[rr][nt] = v; s += v; ss += v * v;
    }
    #pragma unroll
    for (int m2 = 1; m2 <= 8; m2 <<= 1) { s += __shfl_xor(s, m2); ss += __shfl_xor(ss, m2); }
    if (fr == 0) { ps[w][fq * 4 + rr] = s; pss[w][fq * 4 + rr] = ss; }
  }
  __syncthreads();
  #pragma unroll
  for (int rr = 0; rr < 4; ++rr) {
    int row = m0 + fq * 4 + rr;
    int ri = fq * 4 + rr;
    float s = ps[0][ri] + ps[1][ri] + ps[2][ri] + ps[3][ri];
    float ss = pss[0][ri] + pss[1][ri] + pss[2][ri] + pss[3][ri];
    float mean = s * (1.f / 256.f);
    float var = ss * (1.f / 256.f) - mean * mean;
    float rstd = rsqrtf(var + 1e-5f);
    if (row < M) {
      #pragma unroll
      for (int nt = 0; nt < 4; ++nt) {
        int col = w * 64 + nt * 16 + fr;
        out[(size_t)row * 256 + col] = gamma[col] * (y[rr][nt] - mean) * rstd + beta[col];
      }
    }
  }
}

extern "C" void kernel_launch(void* const* d_in, const int* in_sizes, int n_in,
                              void* d_out, int out_size, void* d_ws, size_t ws_size,
                              hipStream_t stream) {
  (void)n_in; (void)out_size; (void)ws_size;
  const float* x     = (const float*)d_in[0];
  const float* pos   = (const float*)d_in[1];
  const int*   batch = (const int*)d_in[2];
  const float* Wqkv  = (const float*)d_in[3];
  const float* Wout  = (const float*)d_in[4];
  const float* freqs = (const float*)d_in[5];
  const float* Wrope = (const float*)d_in[6];
  const float* gamma = (const float*)d_in[7];
  const float* beta  = (const float*)d_in[8];
  float* out = (float*)d_out;

  int N = in_sizes[0] / 256;  // 6137

  // ws layout (ws_size = 256 MiB, verified by R6's fast-path success)
  char* base = (char*)d_ws;
  int*   offs   = (int*)base;                   // @0
  bf16*  QKVb   = (bf16*)(base + 1024);         // N*768*2  = 9,426,432
  bf16*  VT     = (bf16*)(base + 9427456);      // 4,194,304
  bf16*  Wqkv_t = (bf16*)(base + 13621760);     // 393,216
  bf16*  Wout_t = (bf16*)(base + 14014976);     // 131,072
  bf16*  Ob     = (bf16*)(base + 14146048);     // N*256*2  = 3,142,144
  bf16*  biasb  = (bf16*)(base + 17288192);     // ~44 MB bias tiles

  int MBm = (N + 63) / 64;  // 96
  k_pre<<<65, 256, 0, stream>>>(Wqkv, Wout, batch, Wqkv_t, Wout_t, offs, N);
  k_mid<<<MBm * 12 + 8192, 256, 0, stream>>>(x, Wqkv_t, pos, freqs, Wrope, batch, offs,
                                             QKVb, VT, biasb, N, MBm);
  k_attn<<<dim3(32, NGRAPH, 2), 256, 0, stream>>>(QKVb, VT, biasb, offs, Ob);
  k_out_ln<<<(N + 15) / 16, 256, 0, stream>>>(Ob, Wout_t, x, gamma, beta, out, N);
}

// Round 8
// 182.160 us; speedup vs baseline: 1.1278x; 1.0392x over previous
//
#include <hip/hip_runtime.h>
#include <hip/hip_bf16.h>

typedef __hip_bfloat16 bf16;
typedef short bf16x8 __attribute__((ext_vector_type(8)));
typedef float f32x4 __attribute__((ext_vector_type(4)));

#define NGRAPH 16
#define QSCALE 0.17677669529663687f
#define VT_LD 8192  // V^T leading dim: 16 graphs x 512 slots

struct __align__(16) bf8x { bf16 v[8]; };

// load 8 consecutive f32 and convert to a bf16x8 A/B fragment
__device__ __forceinline__ bf16x8 ldcvt8(const float* p) {
  float4 u = *(const float4*)p, v = *(const float4*)(p + 4);
  __align__(16) bf16 tmp[8];
  tmp[0] = __float2bfloat16(u.x); tmp[1] = __float2bfloat16(u.y);
  tmp[2] = __float2bfloat16(u.z); tmp[3] = __float2bfloat16(u.w);
  tmp[4] = __float2bfloat16(v.x); tmp[5] = __float2bfloat16(v.y);
  tmp[6] = __float2bfloat16(v.z); tmp[7] = __float2bfloat16(v.w);
  return *(const bf16x8*)tmp;
}

// ---------------- K1: W transposes (LDS-tiled, coalesced) + graph offsets ----------------
__global__ __launch_bounds__(256) void k_pre(const float* __restrict__ Wqkv,
                                             const float* __restrict__ Wout,
                                             const int* __restrict__ batch,
                                             bf16* __restrict__ Wqkv_t,
                                             bf16* __restrict__ Wout_t,
                                             int* __restrict__ offs, int N) {
  __shared__ float ld[64][65];
  int bid = blockIdx.x, t = threadIdx.x;
  int c = t & 63, r0 = t >> 6;
  if (bid < 48) {  // Wqkv [256][768] -> Wqkv_t [768][256]
    int k0 = (bid & 3) * 64, n0 = (bid >> 2) * 64;
    #pragma unroll
    for (int r = r0; r < 64; r += 4) ld[r][c] = Wqkv[(size_t)(k0 + r) * 768 + n0 + c];
    __syncthreads();
    #pragma unroll
    for (int r = r0; r < 64; r += 4)
      Wqkv_t[(size_t)(n0 + r) * 256 + k0 + c] = __float2bfloat16(ld[c][r]);
  } else if (bid < 64) {  // Wout [256][256] -> Wout_t [256][256]
    int b2 = bid - 48;
    int k0 = (b2 & 3) * 64, n0 = (b2 >> 2) * 64;
    #pragma unroll
    for (int r = r0; r < 64; r += 4) ld[r][c] = Wout[(size_t)(k0 + r) * 256 + n0 + c];
    __syncthreads();
    #pragma unroll
    for (int r = r0; r < 64; r += 4)
      Wout_t[(size_t)(n0 + r) * 256 + k0 + c] = __float2bfloat16(ld[c][r]);
  } else {  // offsets from sorted batch ids
    for (int i = t; i < N; i += 256) {
      if (i == 0) { offs[0] = 0; offs[NGRAPH] = N; }
      else if (batch[i] != batch[i - 1]) offs[batch[i]] = i;
    }
  }
}

// ---------------- K2: merged [QKV GEMM (x f32 direct) | bias precompute] ----------------
// blocks [0, MBm*12): 64x64 GEMM tiles; blocks [MBm*12, +8192): bias tiles.
// Bias inner loop reads freqs/Wrope as WAVE-UNIFORM global loads -> s_load +
// v_fmac(v,s,v); no LDS broadcast traffic in the 128-FMA/pair hot loop.
__global__ __launch_bounds__(256) void k_mid(const float* __restrict__ x,
                                             const bf16* __restrict__ Wqkv_t,
                                             const float* __restrict__ pos,
                                             const float* __restrict__ freqs,
                                             const float* __restrict__ Wrope,
                                             const int* __restrict__ batch,
                                             const int* __restrict__ offs,
                                             bf16* __restrict__ QKVb,
                                             bf16* __restrict__ VT,
                                             bf16* __restrict__ bias,
                                             int N, int MBm) {
  __shared__ __align__(16) char smem[18432];
  int t = threadIdx.x, bid = blockIdx.x;
  int nbg = MBm * 12;
  if (bid < nbg) {
    // ---------------- GEMM role ----------------
    float (*tr)[65] = (float(*)[65])smem;            // 64x65x4 = 16640
    int* rowcol = (int*)(smem + 16640);              // 64x4    = 256
    int w = t >> 6, l = t & 63, fr = l & 15, fq = l >> 4;
    int m0 = (bid % MBm) * 64, n0 = (bid / MBm) * 64;
    bool isV = (n0 >= 512);
    if (isV && t < 64) {
      int m = m0 + t; if (m > N - 1) m = N - 1;
      int b = batch[m];
      rowcol[t] = b * 512 + (m - offs[b]);
    }
    int arow = m0 + w * 16 + fr; if (arow > N - 1) arow = N - 1;
    bf16x8 af[8];
    #pragma unroll
    for (int kt = 0; kt < 8; ++kt)
      af[kt] = ldcvt8(x + (size_t)arow * 256 + kt * 32 + fq * 8);
    f32x4 acc[4];
    #pragma unroll
    for (int nt = 0; nt < 4; ++nt) acc[nt] = (f32x4){0.f, 0.f, 0.f, 0.f};
    #pragma unroll
    for (int nt = 0; nt < 4; ++nt) {
      int brow = n0 + nt * 16 + fr;
      #pragma unroll
      for (int kt = 0; kt < 8; ++kt) {
        bf16x8 bf_ = *(const bf16x8*)(Wqkv_t + (size_t)brow * 256 + kt * 32 + fq * 8);
        acc[nt] = __builtin_amdgcn_mfma_f32_16x16x32_bf16(af[kt], bf_, acc[nt], 0, 0, 0);
      }
    }
    #pragma unroll
    for (int nt = 0; nt < 4; ++nt) {
      int col = n0 + nt * 16 + fr;
      float sc = (col < 256) ? QSCALE : 1.f;
      #pragma unroll
      for (int rr = 0; rr < 4; ++rr) {
        int m = m0 + w * 16 + fq * 4 + rr;
        if (m < N) QKVb[(size_t)m * 768 + col] = __float2bfloat16(acc[nt][rr] * sc);
      }
    }
    if (isV) {
      #pragma unroll
      for (int nt = 0; nt < 4; ++nt)
        #pragma unroll
        for (int rr = 0; rr < 4; ++rr)
          tr[nt * 16 + fr][w * 16 + fq * 4 + rr] = acc[nt][rr];
      __syncthreads();
      int c = t >> 2, r0 = (t & 3) * 16;
      int dg = (n0 - 512) + c;
      #pragma unroll
      for (int i = 0; i < 16; ++i) {
        int r = r0 + i;
        VT[(size_t)dg * VT_LD + rowcol[r]] = __float2bfloat16(tr[c][r]);
      }
    }
  } else {
    // ---------------- bias role: one (graph, 16q, 32j) tile ----------------
    float (*Sb)[16][36] = (float(*)[16][36])smem;    // 8x16x36x4 = 18432 (stride 36: 2-way banks = free)
    int b2 = bid - nbg;
    int b = b2 >> 9;
    int q0 = (b2 & 31) * 16, j0 = ((b2 >> 5) & 15) * 32;
    int off = offs[b], n = offs[b + 1] - off;
    if (q0 >= n || j0 >= n) return;
    int tb = 0;
    for (int g = 0; g < b; ++g) {
      int ng = offs[g + 1] - offs[g];
      tb += ((ng + 15) >> 4) * ((ng + 31) >> 5);
    }
    int jtiles = (n + 31) >> 5;
    bf16* tile = bias + (size_t)(tb + (q0 >> 4) * jtiles + (j0 >> 5)) * 4096;
    int qs = t >> 5, j = t & 31;
    int jg = j0 + j; bool vj = jg < n;
    float jx, jy, jz;
    { int a = (vj ? off + jg : off) * 3; jx = pos[a]; jy = pos[a + 1]; jz = pos[a + 2]; }
    #pragma unroll
    for (int e = 0; e < 2; ++e) {
      int q = qs + 8 * e; int qg = q0 + q; bool vq = qg < n;
      float bv[8];
      #pragma unroll
      for (int h = 0; h < 8; ++h) bv[h] = 0.f;
      if (vq && vj) {
        int a = (off + qg) * 3;
        float dx = pos[a] - jx, dy = pos[a + 1] - jy, dz = pos[a + 2] - jz;
        float dist = sqrtf(dx * dx + dy * dy + dz * dz);
        #pragma unroll
        for (int r = 0; r < 16; ++r) {
          float cv = __cosf(dist * fabsf(freqs[r]));      // freqs[r]: uniform -> SGPR
          #pragma unroll
          for (int h = 0; h < 8; ++h) bv[h] += cv * Wrope[r * 8 + h];  // uniform -> v_fmac(v,s,v)
        }
      }
      #pragma unroll
      for (int h = 0; h < 8; ++h) Sb[h][q][j] = (vq && vj) ? bv[h] : -1e30f;
    }
    __syncthreads();
    int w = t >> 6, l = t & 63, fq = l >> 4, fr = l & 15;
    #pragma unroll
    for (int hh = 0; hh < 2; ++hh) {
      int h = w * 2 + hh;
      __align__(16) bf16 pk[8];
      #pragma unroll
      for (int k = 0; k < 8; ++k)
        pk[k] = __float2bfloat16(Sb[h][fq * 4 + (k & 3)][(k >> 2) * 16 + fr]);
      *(bf16x8*)(tile + h * 512 + l * 8) = *(const bf16x8*)pk;
    }
  }
}

// ---------------- K3: MFMA flash attention — barrier-free, no-max softmax ----------------
__global__ __launch_bounds__(256) void k_attn(const bf16* __restrict__ QKVb,
                                              const bf16* __restrict__ VT,
                                              const bf16* __restrict__ bias,
                                              const int* __restrict__ offs,
                                              bf16* __restrict__ Ob) {
  __shared__ __align__(16) bf16 Pt[4][16][40];
  int b = blockIdx.y, hbase = blockIdx.z * 4;
  int off = offs[b], n = offs[b + 1] - off;
  int q0 = blockIdx.x * 16;
  if (q0 >= n) return;
  int t = threadIdx.x, w = t >> 6, l = t & 63, fr = l & 15, fq = l >> 4;
  int h = hbase + w;
  int tb = 0;
  for (int g = 0; g < b; ++g) {
    int ng = offs[g + 1] - offs[g];
    tb += ((ng + 15) >> 4) * ((ng + 31) >> 5);
  }
  int jtiles = (n + 31) >> 5;
  const bf16* btile = bias + (size_t)(tb + (q0 >> 4) * jtiles) * 4096 + h * 512 + l * 8;
  const bf16* Kb = QKVb + (size_t)off * 768 + 256 + h * 32 + fq * 8;
  const bf16* Vb = VT + (size_t)(h * 32 + fr) * VT_LD + b * 512 + fq * 8;
  int qrow = q0 + fr; bool qv = qrow < n;
  bf16x8 aq = *(const bf16x8*)(QKVb + (size_t)(qv ? off + qrow : off) * 768 + h * 32 + fq * 8);
  if (!qv) aq = (bf16x8){0, 0, 0, 0, 0, 0, 0, 0};
  f32x4 Oa[2];
  Oa[0] = (f32x4){0.f, 0.f, 0.f, 0.f}; Oa[1] = (f32x4){0.f, 0.f, 0.f, 0.f};
  float lacc[4] = {0.f, 0.f, 0.f, 0.f};

#define LOADT(JT, B_, K0_, K1_, V0_, V1_) do {                                   \
    int _jt = (JT); int _k0 = _jt * 32 + fr, _k1 = _k0 + 16;                     \
    B_ = *(const bf8x*)(btile + (size_t)_jt * 4096);                             \
    K0_ = *(const bf16x8*)(Kb + (size_t)((_k0 < n) ? _k0 : 0) * 768);            \
    K1_ = *(const bf16x8*)(Kb + (size_t)((_k1 < n) ? _k1 : 0) * 768);            \
    V0_ = *(const bf16x8*)(Vb + _jt * 32);                                       \
    V1_ = *(const bf16x8*)(Vb + (size_t)16 * VT_LD + _jt * 32);                  \
  } while (0)

  bf8x cb; bf16x8 ck0, ck1, cv0, cv1;
  LOADT(0, cb, ck0, ck1, cv0, cv1);
  for (int jt = 0; jt < jtiles; ++jt) {
    bf8x nb; bf16x8 nk0, nk1, nv0, nv1;
    if (jt + 1 < jtiles) LOADT(jt + 1, nb, nk0, nk1, nv0, nv1);
    f32x4 z = {0.f, 0.f, 0.f, 0.f};
    f32x4 S0 = __builtin_amdgcn_mfma_f32_16x16x32_bf16(aq, ck0, z, 0, 0, 0);
    f32x4 S1 = __builtin_amdgcn_mfma_f32_16x16x32_bf16(aq, ck1, z, 0, 0, 0);
    #pragma unroll
    for (int k = 0; k < 8; ++k) {
      int jti = k >> 2, rr = k & 3;
      float s = (jti ? S1[rr] : S0[rr]) + __bfloat162float(cb.v[k]);
      float p = __expf(s);
      lacc[rr] += p;
      Pt[w][fq * 4 + rr][jti * 16 + fr] = __float2bfloat16(p);
    }
    bf16x8 ap = *(const bf16x8*)&Pt[w][fr][fq * 8];
    Oa[0] = __builtin_amdgcn_mfma_f32_16x16x32_bf16(ap, cv0, Oa[0], 0, 0, 0);
    Oa[1] = __builtin_amdgcn_mfma_f32_16x16x32_bf16(ap, cv1, Oa[1], 0, 0, 0);
    cb = nb; ck0 = nk0; ck1 = nk1; cv0 = nv0; cv1 = nv1;
  }
#undef LOADT
  #pragma unroll
  for (int rr = 0; rr < 4; ++rr) {
    #pragma unroll
    for (int m2 = 1; m2 <= 8; m2 <<= 1) lacc[rr] += __shfl_xor(lacc[rr], m2);
  }
  #pragma unroll
  for (int dh = 0; dh < 2; ++dh)
    #pragma unroll
    for (int rr = 0; rr < 4; ++rr) {
      int row = q0 + fq * 4 + rr;
      if (row < n)
        Ob[(size_t)(off + row) * 256 + h * 32 + dh * 16 + fr] =
            __float2bfloat16(Oa[dh][rr] / lacc[rr]);
    }
}

// ---------------- K4: out-proj GEMM + residual + LN, 16 rows/block (384 blocks) ----------
__global__ __launch_bounds__(256) void k_out_ln(const bf16* __restrict__ A,
                                                const bf16* __restrict__ Bt,
                                                const float* __restrict__ x,
                                                const float* __restrict__ gamma,
                                                const float* __restrict__ beta,
                                                float* __restrict__ out, int M) {
  __shared__ float ps[4][16], pss[4][16];
  int t = threadIdx.x, w = t >> 6, l = t & 63, fr = l & 15, fq = l >> 4;
  int m0 = blockIdx.x * 16;
  int arow = m0 + fr; if (arow > M - 1) arow = M - 1;
  bf16x8 af[8];
  #pragma unroll
  for (int kt = 0; kt < 8; ++kt)
    af[kt] = *(const bf16x8*)(A + (size_t)arow * 256 + kt * 32 + fq * 8);
  f32x4 acc[4];
  #pragma unroll
  for (int nt = 0; nt < 4; ++nt) {
    acc[nt] = (f32x4){0.f, 0.f, 0.f, 0.f};
    int brow = w * 64 + nt * 16 + fr;
    #pragma unroll
    for (int kt = 0; kt < 8; ++kt) {
      bf16x8 bf_ = *(const bf16x8*)(Bt + (size_t)brow * 256 + kt * 32 + fq * 8);
      acc[nt] = __builtin_amdgcn_mfma_f32_16x16x32_bf16(af[kt], bf_, acc[nt], 0, 0, 0);
    }
  }
  float y[4][4];
  #pragma unroll
  for (int rr = 0; rr < 4; ++rr) {
    int row = m0 + fq * 4 + rr;
    int rc = (row < M) ? row : (M - 1);
    float s = 0.f, ss = 0.f;
    #pragma unroll
    for (int nt = 0; nt < 4; ++nt) {
      float v = acc[nt][rr] + x[(size_t)rc * 256 + w * 64 + nt * 16 + fr];
      y[rr][nt] = v; s += v; ss += v * v;
    }
    #pragma unroll
    for (int m2 = 1; m2 <= 8; m2 <<= 1) { s += __shfl_xor(s, m2); ss += __shfl_xor(ss, m2); }
    if (fr == 0) { ps[w][fq * 4 + rr] = s; pss[w][fq * 4 + rr] = ss; }
  }
  __syncthreads();
  #pragma unroll
  for (int rr = 0; rr < 4; ++rr) {
    int row = m0 + fq * 4 + rr;
    int ri = fq * 4 + rr;
    float s = ps[0][ri] + ps[1][ri] + ps[2][ri] + ps[3][ri];
    float ss = pss[0][ri] + pss[1][ri] + pss[2][ri] + pss[3][ri];
    float mean = s * (1.f / 256.f);
    float var = ss * (1.f / 256.f) - mean * mean;
    float rstd = rsqrtf(var + 1e-5f);
    if (row < M) {
      #pragma unroll
      for (int nt = 0; nt < 4; ++nt) {
        int col = w * 64 + nt * 16 + fr;
        out[(size_t)row * 256 + col] = gamma[col] * (y[rr][nt] - mean) * rstd + beta[col];
      }
    }
  }
}

extern "C" void kernel_launch(void* const* d_in, const int* in_sizes, int n_in,
                              void* d_out, int out_size, void* d_ws, size_t ws_size,
                              hipStream_t stream) {
  (void)n_in; (void)out_size; (void)ws_size;
  const float* x     = (const float*)d_in[0];
  const float* pos   = (const float*)d_in[1];
  const int*   batch = (const int*)d_in[2];
  const float* Wqkv  = (const float*)d_in[3];
  const float* Wout  = (const float*)d_in[4];
  const float* freqs = (const float*)d_in[5];
  const float* Wrope = (const float*)d_in[6];
  const float* gamma = (const float*)d_in[7];
  const float* beta  = (const float*)d_in[8];
  float* out = (float*)d_out;

  int N = in_sizes[0] / 256;  // 6137

  char* base = (char*)d_ws;
  int*   offs   = (int*)base;                   // @0
  bf16*  QKVb   = (bf16*)(base + 1024);         // N*768*2  = 9,426,432
  bf16*  VT     = (bf16*)(base + 9427456);      // 4,194,304
  bf16*  Wqkv_t = (bf16*)(base + 13621760);     // 393,216
  bf16*  Wout_t = (bf16*)(base + 14014976);     // 131,072
  bf16*  Ob     = (bf16*)(base + 14146048);     // N*256*2  = 3,142,144
  bf16*  biasb  = (bf16*)(base + 17288192);     // ~44 MB bias tiles

  int MBm = (N + 63) / 64;  // 96
  k_pre<<<65, 256, 0, stream>>>(Wqkv, Wout, batch, Wqkv_t, Wout_t, offs, N);
  k_mid<<<MBm * 12 + 8192, 256, 0, stream>>>(x, Wqkv_t, pos, freqs, Wrope, batch, offs,
                                             QKVb, VT, biasb, N, MBm);
  k_attn<<<dim3(32, NGRAPH, 2), 256, 0, stream>>>(QKVb, VT, biasb, offs, Ob);
  k_out_ln<<<(N + 15) / 16, 256, 0, stream>>>(Ob, Wout_t, x, gamma, beta, out, N);
}

// Round 9
// 181.365 us; speedup vs baseline: 1.1327x; 1.0044x over previous
//
#include <hip/hip_runtime.h>
#include <hip/hip_bf16.h>

typedef __hip_bfloat16 bf16;
typedef short bf16x8 __attribute__((ext_vector_type(8)));
typedef float f32x4 __attribute__((ext_vector_type(4)));

#define NGRAPH 16
#define QSCALE 0.17677669529663687f
#define VT_LD 8192  // V^T leading dim: 16 graphs x 512 slots

// load 8 consecutive f32 and convert to a bf16x8 A/B fragment
__device__ __forceinline__ bf16x8 ldcvt8(const float* p) {
  float4 u = *(const float4*)p, v = *(const float4*)(p + 4);
  __align__(16) bf16 tmp[8];
  tmp[0] = __float2bfloat16(u.x); tmp[1] = __float2bfloat16(u.y);
  tmp[2] = __float2bfloat16(u.z); tmp[3] = __float2bfloat16(u.w);
  tmp[4] = __float2bfloat16(v.x); tmp[5] = __float2bfloat16(v.y);
  tmp[6] = __float2bfloat16(v.z); tmp[7] = __float2bfloat16(v.w);
  return *(const bf16x8*)tmp;
}

// ---------------- K1: W transposes (LDS-tiled, coalesced) + graph offsets ----------------
__global__ __launch_bounds__(256) void k_pre(const float* __restrict__ Wqkv,
                                             const float* __restrict__ Wout,
                                             const int* __restrict__ batch,
                                             bf16* __restrict__ Wqkv_t,
                                             bf16* __restrict__ Wout_t,
                                             int* __restrict__ offs, int N) {
  __shared__ float ld[64][65];
  int bid = blockIdx.x, t = threadIdx.x;
  int c = t & 63, r0 = t >> 6;
  if (bid < 48) {  // Wqkv [256][768] -> Wqkv_t [768][256]
    int k0 = (bid & 3) * 64, n0 = (bid >> 2) * 64;
    #pragma unroll
    for (int r = r0; r < 64; r += 4) ld[r][c] = Wqkv[(size_t)(k0 + r) * 768 + n0 + c];
    __syncthreads();
    #pragma unroll
    for (int r = r0; r < 64; r += 4)
      Wqkv_t[(size_t)(n0 + r) * 256 + k0 + c] = __float2bfloat16(ld[c][r]);
  } else if (bid < 64) {  // Wout [256][256] -> Wout_t [256][256]
    int b2 = bid - 48;
    int k0 = (b2 & 3) * 64, n0 = (b2 >> 2) * 64;
    #pragma unroll
    for (int r = r0; r < 64; r += 4) ld[r][c] = Wout[(size_t)(k0 + r) * 256 + n0 + c];
    __syncthreads();
    #pragma unroll
    for (int r = r0; r < 64; r += 4)
      Wout_t[(size_t)(n0 + r) * 256 + k0 + c] = __float2bfloat16(ld[c][r]);
  } else {  // offsets from sorted batch ids
    for (int i = t; i < N; i += 256) {
      if (i == 0) { offs[0] = 0; offs[NGRAPH] = N; }
      else if (batch[i] != batch[i - 1]) offs[batch[i]] = i;
    }
  }
}

// ---------------- K2: QKV GEMM (x f32 direct-convert), LDS-free MFMA, + V^T ----------------
__global__ __launch_bounds__(256) void k_gemm(const float* __restrict__ x,
                                              const bf16* __restrict__ Wqkv_t,
                                              const int* __restrict__ batch,
                                              const int* __restrict__ offs,
                                              bf16* __restrict__ QKVb,
                                              bf16* __restrict__ VT,
                                              int N, int MBm) {
  __shared__ float tr[64][65];
  __shared__ int rowcol[64];
  int t = threadIdx.x, bid = blockIdx.x;
  int w = t >> 6, l = t & 63, fr = l & 15, fq = l >> 4;
  int m0 = (bid % MBm) * 64, n0 = (bid / MBm) * 64;
  bool isV = (n0 >= 512);
  if (isV && t < 64) {
    int m = m0 + t; if (m > N - 1) m = N - 1;
    int b = batch[m];
    rowcol[t] = b * 512 + (m - offs[b]);
  }
  int arow = m0 + w * 16 + fr; if (arow > N - 1) arow = N - 1;
  bf16x8 af[8];
  #pragma unroll
  for (int kt = 0; kt < 8; ++kt)
    af[kt] = ldcvt8(x + (size_t)arow * 256 + kt * 32 + fq * 8);
  f32x4 acc[4];
  #pragma unroll
  for (int nt = 0; nt < 4; ++nt) acc[nt] = (f32x4){0.f, 0.f, 0.f, 0.f};
  #pragma unroll
  for (int nt = 0; nt < 4; ++nt) {
    int brow = n0 + nt * 16 + fr;
    #pragma unroll
    for (int kt = 0; kt < 8; ++kt) {
      bf16x8 bf_ = *(const bf16x8*)(Wqkv_t + (size_t)brow * 256 + kt * 32 + fq * 8);
      acc[nt] = __builtin_amdgcn_mfma_f32_16x16x32_bf16(af[kt], bf_, acc[nt], 0, 0, 0);
    }
  }
  #pragma unroll
  for (int nt = 0; nt < 4; ++nt) {
    int col = n0 + nt * 16 + fr;
    float sc = (col < 256) ? QSCALE : 1.f;
    #pragma unroll
    for (int rr = 0; rr < 4; ++rr) {
      int m = m0 + w * 16 + fq * 4 + rr;
      if (m < N) QKVb[(size_t)m * 768 + col] = __float2bfloat16(acc[nt][rr] * sc);
    }
  }
  if (isV) {
    #pragma unroll
    for (int nt = 0; nt < 4; ++nt)
      #pragma unroll
      for (int rr = 0; rr < 4; ++rr)
        tr[nt * 16 + fr][w * 16 + fq * 4 + rr] = acc[nt][rr];
    __syncthreads();
    int c = t >> 2, r0 = (t & 3) * 16;
    int dg = (n0 - 512) + c;
    #pragma unroll
    for (int i = 0; i < 16; ++i) {
      int r = r0 + i;
      VT[(size_t)dg * VT_LD + rowcol[r]] = __float2bfloat16(tr[c][r]);
    }
  }
}

// ---------------- K3: fused MFMA flash attention + in-loop RoPE distance bias ----------------
// block = (q-tile 16, graph, head-half of 4). 4 waves, wave = one head.
// Bias tile [4h][16q][32j] produced by all 256 threads into double-buffered LDS
// (cos shared across the block's 4 heads); ONE barrier per 32-j tile.
__global__ __launch_bounds__(256) void k_attn(const float* __restrict__ pos,
                                              const float* __restrict__ freqs,
                                              const float* __restrict__ Wrope,
                                              const bf16* __restrict__ QKVb,
                                              const bf16* __restrict__ VT,
                                              const int* __restrict__ offs,
                                              bf16* __restrict__ Ob) {
  __shared__ float Sb[2][4][16][36];            // stride 36 -> <=2-way banks (free)
  __shared__ __align__(16) bf16 Pt[4][16][40];
  int b = blockIdx.y, hbase = blockIdx.z * 4;
  int off = offs[b], n = offs[b + 1] - off;
  int q0 = blockIdx.x * 16;
  if (q0 >= n) return;
  int t = threadIdx.x, w = t >> 6, l = t & 63, fr = l & 15, fq = l >> 4;
  int h = hbase + w;
  const bf16* Kb = QKVb + (size_t)off * 768 + 256 + h * 32 + fq * 8;
  const bf16* Vb = VT + (size_t)(h * 32 + fr) * VT_LD + b * 512 + fq * 8;
  int qrow = q0 + fr; bool qv = qrow < n;
  bf16x8 aq = *(const bf16x8*)(QKVb + (size_t)(qv ? off + qrow : off) * 768 + h * 32 + fq * 8);
  if (!qv) aq = (bf16x8){0, 0, 0, 0, 0, 0, 0, 0};

  // bias-producer role: thread owns pairs (q=bq, j=bj) and (q=bq+8, j=bj)
  int bq = t >> 5, bj = t & 31;
  float qpx[2], qpy[2], qpz[2]; bool bqv[2];
  #pragma unroll
  for (int e = 0; e < 2; ++e) {
    int qq = q0 + bq + 8 * e; bqv[e] = qq < n;
    int a = (bqv[e] ? off + qq : off) * 3;
    qpx[e] = pos[a]; qpy[e] = pos[a + 1]; qpz[e] = pos[a + 2];
  }

  f32x4 Oa[2];
  Oa[0] = (f32x4){0.f, 0.f, 0.f, 0.f}; Oa[1] = (f32x4){0.f, 0.f, 0.f, 0.f};
  float lacc[4] = {0.f, 0.f, 0.f, 0.f};
  int jtiles = (n + 31) >> 5;

#define PRODUCE(JT, BUF) do {                                                     \
    int _jg = (JT) * 32 + bj; bool _vj = _jg < n;                                 \
    int _a = (_vj ? off + _jg : off) * 3;                                         \
    float _jx = pos[_a], _jy = pos[_a + 1], _jz = pos[_a + 2];                    \
    _Pragma("unroll")                                                             \
    for (int _e = 0; _e < 2; ++_e) {                                              \
      float _b0 = 0.f, _b1 = 0.f, _b2 = 0.f, _b3 = 0.f;                           \
      if (_vj && bqv[_e]) {                                                       \
        float _dx = qpx[_e] - _jx, _dy = qpy[_e] - _jy, _dz = qpz[_e] - _jz;      \
        float _d = sqrtf(_dx * _dx + _dy * _dy + _dz * _dz);                      \
        _Pragma("unroll")                                                         \
        for (int _r = 0; _r < 16; ++_r) {                                         \
          float _cv = __cosf(_d * fabsf(freqs[_r]));                              \
          _b0 += _cv * Wrope[_r * 8 + hbase + 0];                                 \
          _b1 += _cv * Wrope[_r * 8 + hbase + 1];                                 \
          _b2 += _cv * Wrope[_r * 8 + hbase + 2];                                 \
          _b3 += _cv * Wrope[_r * 8 + hbase + 3];                                 \
        }                                                                         \
      }                                                                           \
      int _qi = bq + 8 * _e;                                                      \
      Sb[BUF][0][_qi][bj] = _vj ? _b0 : -1e30f;                                   \
      Sb[BUF][1][_qi][bj] = _vj ? _b1 : -1e30f;                                   \
      Sb[BUF][2][_qi][bj] = _vj ? _b2 : -1e30f;                                   \
      Sb[BUF][3][_qi][bj] = _vj ? _b3 : -1e30f;                                   \
    }                                                                             \
  } while (0)

#define LOADT(JT, K0_, K1_, V0_, V1_) do {                                        \
    int _jt = (JT); int _k0 = _jt * 32 + fr, _k1 = _k0 + 16;                      \
    K0_ = *(const bf16x8*)(Kb + (size_t)((_k0 < n) ? _k0 : 0) * 768);             \
    K1_ = *(const bf16x8*)(Kb + (size_t)((_k1 < n) ? _k1 : 0) * 768);             \
    V0_ = *(const bf16x8*)(Vb + _jt * 32);                                        \
    V1_ = *(const bf16x8*)(Vb + (size_t)16 * VT_LD + _jt * 32);                   \
  } while (0)

  bf16x8 ck0, ck1, cv0, cv1;
  LOADT(0, ck0, ck1, cv0, cv1);
  PRODUCE(0, 0);
  __syncthreads();
  for (int jt = 0; jt < jtiles; ++jt) {
    int par = jt & 1;
    bf16x8 nk0, nk1, nv0, nv1;
    if (jt + 1 < jtiles) {
      LOADT(jt + 1, nk0, nk1, nv0, nv1);     // global prefetch issued early
      PRODUCE(jt + 1, par ^ 1);              // VALU cos work into other buffer
    }
    f32x4 z = {0.f, 0.f, 0.f, 0.f};
    f32x4 S0 = __builtin_amdgcn_mfma_f32_16x16x32_bf16(aq, ck0, z, 0, 0, 0);
    f32x4 S1 = __builtin_amdgcn_mfma_f32_16x16x32_bf16(aq, ck1, z, 0, 0, 0);
    #pragma unroll
    for (int k = 0; k < 8; ++k) {
      int jti = k >> 2, rr = k & 3;
      float s = (jti ? S1[rr] : S0[rr]) + Sb[par][w][fq * 4 + rr][jti * 16 + fr];
      float p = __expf(s);
      lacc[rr] += p;
      Pt[w][fq * 4 + rr][jti * 16 + fr] = __float2bfloat16(p);
    }
    bf16x8 ap = *(const bf16x8*)&Pt[w][fr][fq * 8];
    Oa[0] = __builtin_amdgcn_mfma_f32_16x16x32_bf16(ap, cv0, Oa[0], 0, 0, 0);
    Oa[1] = __builtin_amdgcn_mfma_f32_16x16x32_bf16(ap, cv1, Oa[1], 0, 0, 0);
    ck0 = nk0; ck1 = nk1; cv0 = nv0; cv1 = nv1;
    __syncthreads();
  }
#undef LOADT
#undef PRODUCE
  #pragma unroll
  for (int rr = 0; rr < 4; ++rr) {
    #pragma unroll
    for (int m2 = 1; m2 <= 8; m2 <<= 1) lacc[rr] += __shfl_xor(lacc[rr], m2);
  }
  #pragma unroll
  for (int dh = 0; dh < 2; ++dh)
    #pragma unroll
    for (int rr = 0; rr < 4; ++rr) {
      int row = q0 + fq * 4 + rr;
      if (row < n)
        Ob[(size_t)(off + row) * 256 + h * 32 + dh * 16 + fr] =
            __float2bfloat16(Oa[dh][rr] / lacc[rr]);
    }
}

// ---------------- K4: out-proj GEMM + residual + LN, 16 rows/block (384 blocks) ----------
__global__ __launch_bounds__(256) void k_out_ln(const bf16* __restrict__ A,
                                                const bf16* __restrict__ Bt,
                                                const float* __restrict__ x,
                                                const float* __restrict__ gamma,
                                                const float* __restrict__ beta,
                                                float* __restrict__ out, int M) {
  __shared__ float ps[4][16], pss[4][16];
  int t = threadIdx.x, w = t >> 6, l = t & 63, fr = l & 15, fq = l >> 4;
  int m0 = blockIdx.x * 16;
  int arow = m0 + fr; if (arow > M - 1) arow = M - 1;
  bf16x8 af[8];
  #pragma unroll
  for (int kt = 0; kt < 8; ++kt)
    af[kt] = *(const bf16x8*)(A + (size_t)arow * 256 + kt * 32 + fq * 8);
  f32x4 acc[4];
  #pragma unroll
  for (int nt = 0; nt < 4; ++nt) {
    acc[nt] = (f32x4){0.f, 0.f, 0.f, 0.f};
    int brow = w * 64 + nt * 16 + fr;
    #pragma unroll
    for (int kt = 0; kt < 8; ++kt) {
      bf16x8 bf_ = *(const bf16x8*)(Bt + (size_t)brow * 256 + kt * 32 + fq * 8);
      acc[nt] = __builtin_amdgcn_mfma_f32_16x16x32_bf16(af[kt], bf_, acc[nt], 0, 0, 0);
    }
  }
  float y[4][4];
  #pragma unroll
  for (int rr = 0; rr < 4; ++rr) {
    int row = m0 + fq * 4 + rr;
    int rc = (row < M) ? row : (M - 1);
    float s = 0.f, ss = 0.f;
    #pragma unroll
    for (int nt = 0; nt < 4; ++nt) {
      float v = acc[nt][rr] + x[(size_t)rc * 256 + w * 64 + nt * 16 + fr];
      y[rr][nt] = v; s += v; ss += v * v;
    }
    #pragma unroll
    for (int m2 = 1; m2 <= 8; m2 <<= 1) { s += __shfl_xor(s, m2); ss += __shfl_xor(ss, m2); }
    if (fr == 0) { ps[w][fq * 4 + rr] = s; pss[w][fq * 4 + rr] = ss; }
  }
  __syncthreads();
  #pragma unroll
  for (int rr = 0; rr < 4; ++rr) {
    int row = m0 + fq * 4 + rr;
    int ri = fq * 4 + rr;
    float s = ps[0][ri] + ps[1][ri] + ps[2][ri] + ps[3][ri];
    float ss = pss[0][ri] + pss[1][ri] + pss[2][ri] + pss[3][ri];
    float mean = s * (1.f / 256.f);
    float var = ss * (1.f / 256.f) - mean * mean;
    float rstd = rsqrtf(var + 1e-5f);
    if (row < M) {
      #pragma unroll
      for (int nt = 0; nt < 4; ++nt) {
        int col = w * 64 + nt * 16 + fr;
        out[(size_t)row * 256 + col] = gamma[col] * (y[rr][nt] - mean) * rstd + beta[col];
      }
    }
  }
}

extern "C" void kernel_launch(void* const* d_in, const int* in_sizes, int n_in,
                              void* d_out, int out_size, void* d_ws, size_t ws_size,
                              hipStream_t stream) {
  (void)n_in; (void)out_size; (void)ws_size;
  const float* x     = (const float*)d_in[0];
  const float* pos   = (const float*)d_in[1];
  const int*   batch = (const int*)d_in[2];
  const float* Wqkv  = (const float*)d_in[3];
  const float* Wout  = (const float*)d_in[4];
  const float* freqs = (const float*)d_in[5];
  const float* Wrope = (const float*)d_in[6];
  const float* gamma = (const float*)d_in[7];
  const float* beta  = (const float*)d_in[8];
  float* out = (float*)d_out;

  int N = in_sizes[0] / 256;  // 6137

  char* base = (char*)d_ws;
  int*   offs   = (int*)base;                   // @0
  bf16*  QKVb   = (bf16*)(base + 1024);         // N*768*2  = 9,426,432
  bf16*  VT     = (bf16*)(base + 9427456);      // 4,194,304
  bf16*  Wqkv_t = (bf16*)(base + 13621760);     // 393,216
  bf16*  Wout_t = (bf16*)(base + 14014976);     // 131,072
  bf16*  Ob     = (bf16*)(base + 14146048);     // N*256*2  = 3,142,144

  int MBm = (N + 63) / 64;  // 96
  k_pre<<<65, 256, 0, stream>>>(Wqkv, Wout, batch, Wqkv_t, Wout_t, offs, N);
  k_gemm<<<MBm * 12, 256, 0, stream>>>(x, Wqkv_t, batch, offs, QKVb, VT, N, MBm);
  k_attn<<<dim3(32, NGRAPH, 2), 256, 0, stream>>>(pos, freqs, Wrope, QKVb, VT, offs, Ob);
  k_out_ln<<<(N + 15) / 16, 256, 0, stream>>>(Ob, Wout_t, x, gamma, beta, out, N);
}